// Round 1
// baseline (167.839 us; speedup 1.0000x reference)
//
#include <hip/hip_runtime.h>
#include <math.h>

#define D      4096
#define NPREV  8191
#define NROWS  8192

// ---------------- K1 / K6: out[m] = dot(W[m,:], v)  (+ optional residual) ----
template<bool RESIDUAL>
__global__ void k_matvec_rows(const float* __restrict__ W, const float* __restrict__ v,
                              const float* __restrict__ resid, float* __restrict__ out) {
    int gwave = (blockIdx.x * blockDim.x + threadIdx.x) >> 6;  // one wave per row
    int lane  = threadIdx.x & 63;
    if (gwave >= D) return;
    const float4* Wrow = reinterpret_cast<const float4*>(W + (size_t)gwave * D);
    const float4* v4   = reinterpret_cast<const float4*>(v);
    float acc = 0.f;
    #pragma unroll 4
    for (int i = lane; i < D / 4; i += 64) {
        float4 w = Wrow[i], x = v4[i];
        acc += w.x * x.x + w.y * x.y + w.z * x.z + w.w * x.w;
    }
    #pragma unroll
    for (int off = 32; off; off >>= 1) acc += __shfl_down(acc, off, 64);
    if (lane == 0) out[gwave] = RESIDUAL ? (acc + resid[gwave]) : acc;
}

// ---------------- K2: partial of kq[d] = sum_m q[m] * W[m][d] ----------------
// grid (4, D/MCHUNK), block 256. Each block: 1024-wide float4 column slice,
// MCHUNK rows. Writes part[chunk][d].
#define MCHUNK 64
__global__ void k_colvec_partial(const float* __restrict__ W, const float* __restrict__ q,
                                 float* __restrict__ part) {
    int d4 = blockIdx.x * 256 + threadIdx.x;     // 0..1023 (float4 columns)
    int m0 = blockIdx.y * MCHUNK;
    const float4* W4 = reinterpret_cast<const float4*>(W);
    float4 acc = make_float4(0.f, 0.f, 0.f, 0.f);
    #pragma unroll 4
    for (int m = m0; m < m0 + MCHUNK; ++m) {
        float qm = q[m];
        float4 w = W4[(size_t)m * (D / 4) + d4];
        acc.x += qm * w.x; acc.y += qm * w.y; acc.z += qm * w.z; acc.w += qm * w.w;
    }
    reinterpret_cast<float4*>(part)[(size_t)blockIdx.y * (D / 4) + d4] = acc;
}

// ---------------- reduce: out[d] = sum_c part[c][d] --------------------------
__global__ void k_reduce_chunks(const float* __restrict__ part, float* __restrict__ out,
                                int nchunks) {
    int d = blockIdx.x * 256 + threadIdx.x;      // 0..4095
    float acc = 0.f;
    for (int c = 0; c < nchunks; ++c) acc += part[(size_t)c * D + d];
    out[d] = acc;
}

// ---------------- K3: copy inputs -> d_out[4096..] and logits[n]=inputs[n].kq
__global__ void k_logits_copy(const float* __restrict__ prev, const float* __restrict__ inp,
                              const float* __restrict__ kq, float* __restrict__ io,
                              float* __restrict__ logits) {
    int n    = (blockIdx.x * blockDim.x + threadIdx.x) >> 6;   // one wave per row
    int lane = threadIdx.x & 63;
    if (n >= NROWS) return;
    const float* src = (n < NPREV) ? (prev + (size_t)n * D) : inp;
    const float4* s4 = reinterpret_cast<const float4*>(src);
    const float4* k4 = reinterpret_cast<const float4*>(kq);
    float4* d4 = reinterpret_cast<float4*>(io + (size_t)n * D);
    float acc = 0.f;
    #pragma unroll 4
    for (int i = lane; i < D / 4; i += 64) {
        float4 x = s4[i], k = k4[i];
        d4[i] = x;
        acc += x.x * k.x + x.y * k.y + x.z * k.z + x.w * k.w;
    }
    #pragma unroll
    for (int off = 32; off; off >>= 1) acc += __shfl_down(acc, off, 64);
    if (lane == 0) logits[n] = acc;
}

// ---------------- K4: softmax over 8192 logits -------------------------------
__global__ void k_softmax(const float* __restrict__ logits, float* __restrict__ aw) {
    __shared__ float red[16];
    int t = threadIdx.x;                 // 1024 threads
    int wid = t >> 6, lane = t & 63;
    float vals[8];
    float mx = -INFINITY;
    #pragma unroll
    for (int i = 0; i < 8; ++i) { vals[i] = logits[t + i * 1024]; mx = fmaxf(mx, vals[i]); }
    #pragma unroll
    for (int off = 32; off; off >>= 1) mx = fmaxf(mx, __shfl_down(mx, off, 64));
    if (lane == 0) red[wid] = mx;
    __syncthreads();
    float mall = red[0];
    #pragma unroll
    for (int i = 1; i < 16; ++i) mall = fmaxf(mall, red[i]);
    __syncthreads();
    float s = 0.f;
    #pragma unroll
    for (int i = 0; i < 8; ++i) { vals[i] = expf(vals[i] - mall); s += vals[i]; }
    #pragma unroll
    for (int off = 32; off; off >>= 1) s += __shfl_down(s, off, 64);
    if (lane == 0) red[wid] = s;
    __syncthreads();
    float tot = 0.f;
    #pragma unroll
    for (int i = 0; i < 16; ++i) tot += red[i];
    float inv = 1.f / tot;
    #pragma unroll
    for (int i = 0; i < 8; ++i) aw[t + i * 1024] = vals[i] * inv;
}

// ---------------- K5: partial of ctx[d] = sum_n aw[n] * inputs[n][d] ---------
// grid (4, NROWS/NCHUNK), block 256.
#define NCHUNK 64
__global__ void k_ctx_partial(const float* __restrict__ io, const float* __restrict__ aw,
                              float* __restrict__ part) {
    int d4 = blockIdx.x * 256 + threadIdx.x;
    int n0 = blockIdx.y * NCHUNK;
    const float4* io4 = reinterpret_cast<const float4*>(io);
    float4 acc = make_float4(0.f, 0.f, 0.f, 0.f);
    #pragma unroll 4
    for (int n = n0; n < n0 + NCHUNK; ++n) {
        float a = aw[n];
        float4 x = io4[(size_t)n * (D / 4) + d4];
        acc.x += a * x.x; acc.y += a * x.y; acc.z += a * x.z; acc.w += a * x.w;
    }
    reinterpret_cast<float4*>(part)[(size_t)blockIdx.y * (D / 4) + d4] = acc;
}

extern "C" void kernel_launch(void* const* d_in, const int* in_sizes, int n_in,
                              void* d_out, int out_size, void* d_ws, size_t ws_size,
                              hipStream_t stream) {
    const float* prev = (const float*)d_in[0];   // (8191, 4096)
    const float* inp  = (const float*)d_in[1];   // (4096,)
    const float* W_Q  = (const float*)d_in[2];   // (4096, 4096)
    const float* W_K  = (const float*)d_in[3];
    const float* W_V  = (const float*)d_in[4];
    float* out = (float*)d_out;                  // [0:4096]=output, [4096:]=inputs

    float* ws      = (float*)d_ws;
    float* query   = ws;                          // 4096
    float* kq      = ws + 4096;                   // 4096
    float* logits  = ws + 8192;                   // 8192
    float* aw      = ws + 16384;                  // 8192
    float* ctx_in  = ws + 24576;                  // 4096
    float* kqpart  = ws + 28672;                  // 64 * 4096
    float* ctxpart = ws + 28672 + 64 * D;         // 128 * 4096

    float* io = out + D;                          // the "inputs" output region

    // 1. query = W_Q @ inp
    k_matvec_rows<false><<<1024, 256, 0, stream>>>(W_Q, inp, nullptr, query);
    // 2. kq = W_K^T @ query
    k_colvec_partial<<<dim3(4, D / MCHUNK), 256, 0, stream>>>(W_K, query, kqpart);
    k_reduce_chunks<<<16, 256, 0, stream>>>(kqpart, kq, D / MCHUNK);
    // 3. copy inputs to d_out, logits = inputs @ kq
    k_logits_copy<<<2048, 256, 0, stream>>>(prev, inp, kq, io, logits);
    // 4. softmax
    k_softmax<<<1, 1024, 0, stream>>>(logits, aw);
    // 5. ctx_in = aw @ inputs
    k_ctx_partial<<<dim3(4, NROWS / NCHUNK), 256, 0, stream>>>(io, aw, ctxpart);
    k_reduce_chunks<<<16, 256, 0, stream>>>(ctxpart, ctx_in, NROWS / NCHUNK);
    // 6. output = W_V @ ctx_in + inp
    k_matvec_rows<true><<<1024, 256, 0, stream>>>(W_V, ctx_in, inp, out);
}

// Round 2
// 165.151 us; speedup vs baseline: 1.0163x; 1.0163x over previous
//
#include <hip/hip_runtime.h>
#include <math.h>

#define D      4096
#define NPREV  8191
#define NROWS  8192

// ---------------- K1 / K6: out[m] = dot(W[m,:], v)  (+ optional residual) ----
template<bool RESIDUAL>
__global__ void k_matvec_rows(const float* __restrict__ W, const float* __restrict__ v,
                              const float* __restrict__ resid, float* __restrict__ out) {
    int gwave = (blockIdx.x * blockDim.x + threadIdx.x) >> 6;  // one wave per row
    int lane  = threadIdx.x & 63;
    if (gwave >= D) return;
    const float4* Wrow = reinterpret_cast<const float4*>(W + (size_t)gwave * D);
    const float4* v4   = reinterpret_cast<const float4*>(v);
    float acc = 0.f;
    #pragma unroll 4
    for (int i = lane; i < D / 4; i += 64) {
        float4 w = Wrow[i], x = v4[i];
        acc += w.x * x.x + w.y * x.y + w.z * x.z + w.w * x.w;
    }
    #pragma unroll
    for (int off = 32; off; off >>= 1) acc += __shfl_down(acc, off, 64);
    if (lane == 0) out[gwave] = RESIDUAL ? (acc + resid[gwave]) : acc;
}

// ---------------- K2: partial of kq[d] = sum_m q[m] * W[m][d] ----------------
#define MCHUNK 64
__global__ void k_colvec_partial(const float* __restrict__ W, const float* __restrict__ q,
                                 float* __restrict__ part) {
    int d4 = blockIdx.x * 256 + threadIdx.x;     // 0..1023 (float4 columns)
    int m0 = blockIdx.y * MCHUNK;
    const float4* W4 = reinterpret_cast<const float4*>(W);
    float4 acc = make_float4(0.f, 0.f, 0.f, 0.f);
    #pragma unroll 4
    for (int m = m0; m < m0 + MCHUNK; ++m) {
        float qm = q[m];
        float4 w = W4[(size_t)m * (D / 4) + d4];
        acc.x += qm * w.x; acc.y += qm * w.y; acc.z += qm * w.z; acc.w += qm * w.w;
    }
    reinterpret_cast<float4*>(part)[(size_t)blockIdx.y * (D / 4) + d4] = acc;
}

__global__ void k_reduce_chunks(const float* __restrict__ part, float* __restrict__ out,
                                int nchunks) {
    int d = blockIdx.x * 256 + threadIdx.x;      // 0..4095
    float acc = 0.f;
    for (int c = 0; c < nchunks; ++c) acc += part[(size_t)c * D + d];
    out[d] = acc;
}

// ---------------- K3: fused flash — copy + logits + block softmax + ctx partial
// FB blocks x 256 threads; each block owns FR = NROWS/FB consecutive rows.
template<int FB>
__global__ void k_flash(const float* __restrict__ prev, const float* __restrict__ inp,
                        const float* __restrict__ kq, float* __restrict__ io,
                        float* __restrict__ ms, float* __restrict__ ctxpart) {
    constexpr int FR = NROWS / FB;
    __shared__ float s_log[FR];
    __shared__ float s_e[FR];
    int n0 = blockIdx.x * FR;
    int t = threadIdx.x;
    int wid = t >> 6, lane = t & 63;
    const float4* k4 = reinterpret_cast<const float4*>(kq);

    // Phase A: copy rows to io, logits into LDS (wave per row)
    for (int r = wid; r < FR; r += 4) {
        int n = n0 + r;
        const float* src = (n < NPREV) ? (prev + (size_t)n * D) : inp;
        const float4* s4 = reinterpret_cast<const float4*>(src);
        float4* d4 = reinterpret_cast<float4*>(io + (size_t)n * D);
        float acc = 0.f;
        #pragma unroll 4
        for (int i = lane; i < D / 4; i += 64) {
            float4 x = s4[i], k = k4[i];
            d4[i] = x;
            acc += x.x * k.x + x.y * k.y + x.z * k.z + x.w * k.w;
        }
        #pragma unroll
        for (int off = 32; off; off >>= 1) acc += __shfl_down(acc, off, 64);
        if (lane == 0) s_log[r] = acc;
    }
    __syncthreads();

    // Phase B: block-local softmax stats
    float m_b = -INFINITY;
    #pragma unroll 8
    for (int r = 0; r < FR; ++r) m_b = fmaxf(m_b, s_log[r]);
    if (t < FR) s_e[t] = __expf(s_log[t] - m_b);
    __syncthreads();
    float s_b = 0.f;
    #pragma unroll 8
    for (int r = 0; r < FR; ++r) s_b += s_e[r];

    // Phase C: ctx partial over this block's rows, re-reading from prev (L3-hot).
    // Thread t owns float4 columns {t, t+256, t+512, t+768}.
    float4 a0 = make_float4(0.f,0.f,0.f,0.f), a1 = a0, a2 = a0, a3 = a0;
    for (int r = 0; r < FR; ++r) {
        int n = n0 + r;
        const float* src = (n < NPREV) ? (prev + (size_t)n * D) : inp;
        const float4* s4 = reinterpret_cast<const float4*>(src);
        float e = s_e[r];
        float4 x0 = s4[t], x1 = s4[t + 256], x2 = s4[t + 512], x3 = s4[t + 768];
        a0.x += e * x0.x; a0.y += e * x0.y; a0.z += e * x0.z; a0.w += e * x0.w;
        a1.x += e * x1.x; a1.y += e * x1.y; a1.z += e * x1.z; a1.w += e * x1.w;
        a2.x += e * x2.x; a2.y += e * x2.y; a2.z += e * x2.z; a2.w += e * x2.w;
        a3.x += e * x3.x; a3.y += e * x3.y; a3.z += e * x3.z; a3.w += e * x3.w;
    }
    float4* cp = reinterpret_cast<float4*>(ctxpart + (size_t)blockIdx.x * D);
    cp[t] = a0; cp[t + 256] = a1; cp[t + 512] = a2; cp[t + 768] = a3;
    if (t == 0) { ms[2 * blockIdx.x] = m_b; ms[2 * blockIdx.x + 1] = s_b; }
}

// ---------------- K4: combine partials -> normalized ctx ---------------------
template<int FB>
__global__ void k_combine(const float* __restrict__ ms, const float* __restrict__ ctxpart,
                          float* __restrict__ ctx) {
    __shared__ float sm[2 * FB];
    int t = threadIdx.x;  // 256
    for (int i = t; i < 2 * FB; i += 256) sm[i] = ms[i];
    __syncthreads();
    float M = -INFINITY;
    #pragma unroll 8
    for (int b = 0; b < FB; ++b) M = fmaxf(M, sm[2 * b]);
    float S = 0.f;
    #pragma unroll 8
    for (int b = 0; b < FB; ++b) S += __expf(sm[2 * b] - M) * sm[2 * b + 1];
    int d4 = blockIdx.x * 256 + t;   // 4 blocks -> 1024 float4 columns
    float4 acc = make_float4(0.f, 0.f, 0.f, 0.f);
    for (int b = 0; b < FB; ++b) {
        float w = __expf(sm[2 * b] - M);
        float4 x = reinterpret_cast<const float4*>(ctxpart)[(size_t)b * (D / 4) + d4];
        acc.x += w * x.x; acc.y += w * x.y; acc.z += w * x.z; acc.w += w * x.w;
    }
    float inv = 1.f / S;
    acc.x *= inv; acc.y *= inv; acc.z *= inv; acc.w *= inv;
    reinterpret_cast<float4*>(ctx)[d4] = acc;
}

extern "C" void kernel_launch(void* const* d_in, const int* in_sizes, int n_in,
                              void* d_out, int out_size, void* d_ws, size_t ws_size,
                              hipStream_t stream) {
    const float* prev = (const float*)d_in[0];   // (8191, 4096)
    const float* inp  = (const float*)d_in[1];   // (4096,)
    const float* W_Q  = (const float*)d_in[2];
    const float* W_K  = (const float*)d_in[3];
    const float* W_V  = (const float*)d_in[4];
    float* out = (float*)d_out;                  // [0:4096]=output, [4096:]=inputs
    float* io  = out + D;

    float* ws      = (float*)d_ws;
    float* query   = ws;                          // 4096
    float* kq      = ws + D;                      // 4096
    float* kqpart  = ws + 2 * D;                  // 64 * 4096
    float* ms      = ws + 2 * D + 64 * D;         // 512
    float* ctxpart = ms + 512;                    // FB * 4096
    // ctx goes after ctxpart (sized by FB below)

    // 1. query = W_Q @ inp
    k_matvec_rows<false><<<1024, 256, 0, stream>>>(W_Q, inp, nullptr, query);
    // 2. kq = W_K^T @ query
    k_colvec_partial<<<dim3(4, D / MCHUNK), 256, 0, stream>>>(W_K, query, kqpart);
    k_reduce_chunks<<<16, 256, 0, stream>>>(kqpart, kq, D / MCHUNK);

    // 3-5. flash + combine (FB chosen by workspace budget) + W_V matvec
    size_t need256 = (size_t)(2 * D + 64 * D + 512 + 256 * D + D) * sizeof(float);
    if (ws_size >= need256) {
        constexpr int FB = 256;
        float* ctx = ctxpart + FB * D;
        k_flash<FB><<<FB, 256, 0, stream>>>(prev, inp, kq, io, ms, ctxpart);
        k_combine<FB><<<4, 256, 0, stream>>>(ms, ctxpart, ctx);
        k_matvec_rows<true><<<1024, 256, 0, stream>>>(W_V, ctx, inp, out);
    } else {
        constexpr int FB = 128;
        float* ctx = ctxpart + FB * D;
        k_flash<FB><<<FB, 256, 0, stream>>>(prev, inp, kq, io, ms, ctxpart);
        k_combine<FB><<<4, 256, 0, stream>>>(ms, ctxpart, ctx);
        k_matvec_rows<true><<<1024, 256, 0, stream>>>(W_V, ctx, inp, out);
    }
}